// Round 3
// baseline (86.923 us; speedup 1.0000x reference)
//
#include <hip/hip_runtime.h>
#include <math.h>

// B=8, N=1024, D=128.  kv[b,n,512] = [k_mu | v_mu | k_sigma | v_sigma]
// 3-kernel plan, V-only prepass, LDS-diet actor (R3):
//  1) prepass: V side only (cols 128/384) fp32 -> bf16 MFMA-fragment
//     order. b = blockIdx&7 so fragV[b] is written on XCD b -- the same
//     XCD the actor (blockIdx%8==b) reads it from (R2 wrote each b from
//     all 8 XCDs -> cross-XCD L2 misses). Seeds 8 log-prob slots.
//  2) actor: S^T = V.K^T. Block = 512 thr (8 waves), 64 i x 256 j (jh
//     quarter). K staged fp32->bf16 into MFMA-frag LDS (prologue-only
//     cost, verified bit-exact R1). V from prepass output (bf16x8
//     contiguous -- R1 showed in-loop fp32+cvt costs +8us; never).
//     LDS DIET (R3): stage only the 64 i-positions + 256 j-positions
//     this block uses (4.75->3.75 KB vs 12), and alias wacc onto sK
//     (dead after jt loop). 56 KB -> ~36 KB => 4 blocks/CU (32-wave
//     cap) instead of 2 -- 2x latency hiding for the L2-latency V
//     loads / rsqrt TRANS chain. Inner loop untouched.
//  3) tail: 128 blocks x 64 thr; sums 4 jh partials, tanh-normal math
//     via ONE __expf + ONE __logf per component:
//       softplus(t)+softplus(-t) = |t| + 2*log(1+E), E=exp(-|t|)
//       tanh(p) = sign(p)*(1-E)/(1+E)   (same E, t=2p)
//     per-wave log_prob reduce + atomicAdd.
// NOTE: 512-thread blocks + plain __launch_bounds__(512) is the only
// config that never spilled (VGPR 52-60, R8-R12). Never use the
// min-waves arg (R5: VGPR=64 clamp + 100MB spill) or 1024-thr blocks
// (R11: same). No __threadfence / cross-block merge (R9: wbl2 storms).
// Plain bf16 is accuracy-safe: absmax 4096 identical for fp32 /
// split-bf16 / bf16 runs (accumulation-order noise dominates).

#define NTOK 1024
#define LPCONST 14147.0828114f   // -3072*ln(0.01)

typedef __bf16 bf16x8 __attribute__((ext_vector_type(8)));
typedef float f32x4 __attribute__((ext_vector_type(4)));
typedef unsigned short ushort8v __attribute__((ext_vector_type(8)));
#define MFMA(a, b, c) __builtin_amdgcn_mfma_f32_16x16x32_bf16(a, b, c, 0, 0, 0)

__device__ __forceinline__ unsigned short to_bf16(float x) {
    return (unsigned short)((__float_as_uint(x) + 0x8000u) >> 16);
}

__device__ __forceinline__ ushort8v pack8(float4 a, float4 b) {
    ushort8v u;
    u[0] = to_bf16(a.x); u[1] = to_bf16(a.y); u[2] = to_bf16(a.z); u[3] = to_bf16(a.w);
    u[4] = to_bf16(b.x); u[5] = to_bf16(b.y); u[6] = to_bf16(b.z); u[7] = to_bf16(b.w);
    return u;
}

// ---------------- prepass: V side only, XCD-aligned ----------------
__global__ __launch_bounds__(256) void prepass_kernel(
    const float* __restrict__ kv, unsigned short* __restrict__ frag,
    float* __restrict__ out)
{
    if (blockIdx.x == 0 && threadIdx.x < 8)
        out[8 * NTOK * 3 + threadIdx.x] = LPCONST;   // seed log-prob slots

    const int b = blockIdx.x & 7;                    // XCD-local to actor's b
    const int g = (blockIdx.x >> 3) * 256 + threadIdx.x;   // 0..16383 per b
    const int lane = g & 63;
    const int kc   = (g >> 6) & 3;
    const int tile = (g >> 8) & 63;

    const int row = tile * 16 + (lane & 15);
    const int kof = kc * 32 + (lane >> 4) * 8;
    const float* gp = kv + ((size_t)b * NTOK + row) * 512 + 128 + kof;  // v_mu
    const float4 m0 = *(const float4*)gp;
    const float4 m1 = *(const float4*)(gp + 4);
    const float4 s0 = *(const float4*)(gp + 256);   // v_sigma (col 384+kof)
    const float4 s1 = *(const float4*)(gp + 260);

    unsigned short* cp = frag + (size_t)(b * 64 + tile) * 4096 + kc * 1024 + lane * 8;
    *(ushort8v*)(cp + 0)   = pack8(m0, m1);   // arr0 mu
    *(ushort8v*)(cp + 512) = pack8(s0, s1);   // arr1 sg
}

// ---------------- gemm^T + geometry, 64 i x 256 j per block ----------------
__global__ __launch_bounds__(512) void actor_kernel(
    const float* __restrict__ kv, const unsigned short* __restrict__ fragV,
    const float* __restrict__ pos, float* __restrict__ partial)
{
    const int t = threadIdx.x;
    const int w = t >> 6;        // wave 0..7
    const int lane = t & 63;
    const int q = lane >> 4;
    const int r16 = lane & 15;
    const int b   = blockIdx.x & 7;
    const int jh  = (blockIdx.x >> 3) & 3;   // j quarter
    const int ibx = blockIdx.x >> 5;         // 0..15
    const int i0 = ibx * 64;

    const float* kvb  = kv + (size_t)b * NTOK * 512;
    const float* posb = pos + (size_t)b * NTOK * 3;

    __shared__ __align__(16) unsigned short sK[16384];  // 32 KB: 4 K tiles; wacc aliases after jt loop
    __shared__ __align__(16) float spi[64 * 3];         // this block's i-positions
    __shared__ __align__(16) float spj[256 * 3];        // this block's j-quarter positions
    float* wacc = (float*)sK;                           // 8*64*6 floats = 12 KB < 32 KB

    // ---- stage K: fp32 rows -> bf16 MFMA-fragment order in LDS ----
    // thread t -> row ri = t>>3 (of 64), col-group cg = t&7 (16 cols each).
    // frag chunk [tile][kc]: ushort idx = (g*16 + row%16)*8 + e,
    // g = (k - kc*32)/8.  cg*16 = (cg>>1)*32 + (cg&1)*16.  (verified R1)
    {
        const int ri = t >> 3;
        const int cg = t & 7;
        const float* gp = kvb + (size_t)(i0 + ri) * 512 + cg * 16;
        const float4 m0 = *(const float4*)(gp);
        const float4 m1 = *(const float4*)(gp + 4);
        const float4 m2 = *(const float4*)(gp + 8);
        const float4 m3 = *(const float4*)(gp + 12);
        const float4 s0 = *(const float4*)(gp + 256);
        const float4 s1 = *(const float4*)(gp + 260);
        const float4 s2 = *(const float4*)(gp + 264);
        const float4 s3 = *(const float4*)(gp + 268);
        unsigned short* dp = sK + (ri >> 4) * 4096 + (cg >> 1) * 1024
                           + ((cg & 1) * 32 + (ri & 15)) * 8;
        *(ushort8v*)(dp)       = pack8(m0, m1);   // g0,   arr0 mu
        *(ushort8v*)(dp + 128) = pack8(m2, m3);   // g0+1, arr0 mu
        *(ushort8v*)(dp + 512) = pack8(s0, s1);   // g0,   arr1 sg
        *(ushort8v*)(dp + 640) = pack8(s2, s3);   // g0+1, arr1 sg
    }
    // ---- stage only the positions this block touches ----
    if (t < 240) {
        if (t < 48)  *(float4*)&spi[t * 4] = *(const float4*)&posb[i0 * 3 + t * 4];
        else { const int v = t - 48;
               *(float4*)&spj[v * 4] = *(const float4*)&posb[jh * 768 + v * 4]; }
    }
    __syncthreads();

    // lane's i per tile (C column) is fixed
    float pix[4], piy[4], piz[4];
    #pragma unroll
    for (int tile = 0; tile < 4; ++tile) {
        pix[tile] = spi[(tile * 16 + r16) * 3 + 0];
        piy[tile] = spi[(tile * 16 + r16) * 3 + 1];
        piz[tile] = spi[(tile * 16 + r16) * 3 + 2];
    }

    float am[4][3] = {};   // [tile][c]
    float al[4][3] = {};

    const int jtile0 = jh * 16 + w * 2;   // this wave's first 16-j tile
    const unsigned short* vbase =
        fragV + (size_t)(b * 64 + jtile0) * 4096 + lane * 8;
    const int klofs = lane * 8;

    #pragma unroll
    for (int jt = 0; jt < 2; ++jt) {
        const unsigned short* vp = vbase + jt * 4096;
        f32x4 accm[4], accs[4];
        #pragma unroll
        for (int tile = 0; tile < 4; ++tile) {
            accm[tile] = (f32x4){0.f, 0.f, 0.f, 0.f};
            accs[tile] = (f32x4){0.f, 0.f, 0.f, 0.f};
        }
        #pragma unroll
        for (int kc = 0; kc < 4; ++kc) {
            const bf16x8 Vm = *(const bf16x8*)(vp + kc * 1024);
            const bf16x8 Vs = *(const bf16x8*)(vp + kc * 1024 + 512);
            #pragma unroll
            for (int tile = 0; tile < 4; ++tile) {
                const bf16x8 Km = *(const bf16x8*)&sK[tile * 4096 + kc * 1024 + klofs];
                const bf16x8 Ks = *(const bf16x8*)&sK[tile * 4096 + kc * 1024 + 512 + klofs];
                accm[tile] = MFMA(Vm, Km, accm[tile]);   // C[row=j][col=i]
                accs[tile] = MFMA(Vs, Ks, accs[tile]);
            }
        }
        // ---- fold this tile's 4 j's (rows q*4+reg) into per-i sums ----
        const int jl = (w * 2 + jt) * 16 + q * 4;   // local j in [0,256)
        #pragma unroll
        for (int reg = 0; reg < 4; ++reg) {
            const float* pj = &spj[(jl + reg) * 3];  // LDS broadcast
            const float pjx = pj[0], pjy = pj[1], pjz = pj[2];
            #pragma unroll
            for (int tile = 0; tile < 4; ++tile) {
                const float dx = pix[tile] - pjx;
                const float dy = piy[tile] - pjy;
                const float dz = piz[tile] - pjz;
                const float d2 = dx * dx + dy * dy + dz * dz;
                const float inv = d2 > 0.f ? rsqrtf(d2) : 0.f;  // i==j -> 0
                const float wm = accm[tile][reg] * inv;
                const float ws = accs[tile][reg] * inv;
                am[tile][0] = fmaf(dx, wm, am[tile][0]);
                am[tile][1] = fmaf(dy, wm, am[tile][1]);
                am[tile][2] = fmaf(dz, wm, am[tile][2]);
                al[tile][0] = fmaf(dx, ws, al[tile][0]);
                al[tile][1] = fmaf(dy, ws, al[tile][1]);
                al[tile][2] = fmaf(dz, ws, al[tile][2]);
            }
        }
    }

    // ---- reduce over the 4 q-groups (lanes r16, +16, +32, +48) ----
    #pragma unroll
    for (int tile = 0; tile < 4; ++tile)
        #pragma unroll
        for (int c = 0; c < 3; ++c) {
            float vm = am[tile][c], vl = al[tile][c];
            vm += __shfl_xor(vm, 16, 64); vm += __shfl_xor(vm, 32, 64);
            vl += __shfl_xor(vl, 16, 64); vl += __shfl_xor(vl, 32, 64);
            am[tile][c] = vm; al[tile][c] = vl;
        }

    // ---- cross-wave combine via LDS (wacc aliases sK: sync first) ----
    __syncthreads();   // all waves done reading sK before overwrite
    if (lane < 16) {
        #pragma unroll
        for (int tile = 0; tile < 4; ++tile) {
            float* p = wacc + (w * 64 + tile * 16 + r16) * 6;
            p[0] = am[tile][0]; p[1] = am[tile][1]; p[2] = am[tile][2];
            p[3] = al[tile][0]; p[4] = al[tile][1]; p[5] = al[tile][2];
        }
    }
    __syncthreads();
    if (t < 384) {
        float v = 0.f;
        #pragma unroll
        for (int ww = 0; ww < 8; ++ww) v += wacc[ww * 384 + t];
        const int row = t / 6, c = t - row * 6;
        partial[((size_t)((jh * 8 + b) * NTOK) + i0 + row) * 6 + c] = v;
    }
}

// ---------------- tail ----------------
__global__ __launch_bounds__(64) void actor_tail_kernel(
    const float* __restrict__ partial, const float* __restrict__ eps,
    float* __restrict__ out)
{
    const int b = blockIdx.x >> 4;
    const int i = (blockIdx.x & 15) * 64 + threadIdx.x;
    const int gi = b * NTOK + i;

    float am[3] = {}, al[3] = {};
    #pragma unroll
    for (int jh = 0; jh < 4; ++jh) {
        const float* p = partial + (((size_t)jh * 8 + b) * NTOK + i) * 6;
        const float2 v0 = *(const float2*)(p);
        const float2 v1 = *(const float2*)(p + 2);
        const float2 v2 = *(const float2*)(p + 4);
        am[0] += v0.x; am[1] += v0.y; am[2] += v1.x;
        al[0] += v1.y; al[1] += v2.x; al[2] += v2.y;
    }

    float lp = 0.f;
    #pragma unroll
    for (int c = 0; c < 3; ++c) {
        const float als = fminf(fmaxf(al[c], -20.f), 2.f);
        const float sd = __expf(als);
        const float e = eps[gi * 3 + c];
        const float pre = fmaf(sd, e, am[c]);
        // E = exp(-2|pre|):  tanh(pre) = sign*(1-E)/(1+E);
        // softplus(2pre)+softplus(-2pre) = 2|pre| + 2*log(1+E)
        const float a2 = 2.f * fabsf(pre);
        const float E = __expf(-a2);
        const float th = (1.f - E) / (1.f + E);
        out[gi * 3 + c] = copysignf(th, pre) * 0.01f;
        lp += fmaf(-0.5f * e, e, -als) - 2.3052328944f + a2 + 2.f * __logf(1.f + E);
    }

    #pragma unroll
    for (int m = 1; m < 64; m <<= 1) lp += __shfl_xor(lp, m, 64);
    if (threadIdx.x == 0) atomicAdd(out + NTOK * 8 * 3 + b, lp);
}

extern "C" void kernel_launch(void* const* d_in, const int* in_sizes, int n_in,
                              void* d_out, int out_size, void* d_ws, size_t ws_size,
                              hipStream_t stream) {
    const float* kv = (const float*)d_in[0];
    const float* pos = (const float*)d_in[1];
    const float* eps = (const float*)d_in[2];
    float* out = (float*)d_out;
    unsigned short* fragV = (unsigned short*)d_ws;                // 4 MiB
    float* partial = (float*)((char*)d_ws + 4194304);             // 768 KiB

    prepass_kernel<<<dim3(512), 256, 0, stream>>>(kv, fragV, out);
    actor_kernel<<<dim3(512), 512, 0, stream>>>(kv, fragV, pos, partial);
    actor_tail_kernel<<<dim3(128), 64, 0, stream>>>(partial, eps, out);
}

// Round 4
// 84.350 us; speedup vs baseline: 1.0305x; 1.0305x over previous
//
#include <hip/hip_runtime.h>
#include <math.h>

// B=8, N=1024, D=128.  kv[b,n,512] = [k_mu | v_mu | k_sigma | v_sigma]
// 3-kernel plan, V-only prepass, 32-i actor blocks (R4):
//  1) prepass: V side only (cols 128/384) fp32 -> bf16 MFMA-fragment
//     order. b = blockIdx&7 so fragV[b] is written on XCD b -- the same
//     XCD the actor (blockIdx%8==b) reads it from. Seeds log-prob slots.
//  2) actor: S^T = V.K^T. Block = 512 thr (8 waves), 32 i x 256 j (jh
//     quarter), grid 1024 = 4 blocks/CU = 32 waves/CU (HW cap; R3's
//     512-block grid only supplied 2 blocks/CU -- grid-limited, not
//     LDS-limited). sK = 2 K tiles = 16 KB; LDS ~19 KB -> capacity 8.
//     K staged fp32->bf16 into MFMA-frag LDS (prologue halved vs R3).
//     V from prepass fragV (bf16x8 contiguous; R1: never fp32+cvt in
//     the inner loop). Chip K traffic halves (32 MB), V doubles
//     (128 MB L2, ~+2us) -- net win if latency-bound.
//     C[row=j][col=i]: lane col fixed per tile; 4 regs = 4 j; geometric
//     fold in-register; q-group shuffle; wacc aliases sK; partial.
//  3) tail: 128 blocks x 64 thr; sums 4 jh partials, tanh-normal math
//     via ONE __expf + ONE __logf per component:
//       softplus(t)+softplus(-t) = |t| + 2*log(1+E), E=exp(-|t|)
//       tanh(p) = sign(p)*(1-E)/(1+E)   (same E, t=2p)
//     per-wave log_prob reduce + atomicAdd.
// NOTE: 512-thread blocks + plain __launch_bounds__(512) (VGPR 52-60,
// no spill). Never the min-waves arg (VGPR=64 clamp + spill) or
// 1024-thr blocks. No __threadfence / cross-block merge (wbl2 storms).
// Wave->j mapping unchanged vs R2/R3 => bit-identical accumulation
// order => absmax must stay exactly 4096.

#define NTOK 1024
#define LPCONST 14147.0828114f   // -3072*ln(0.01)

typedef __bf16 bf16x8 __attribute__((ext_vector_type(8)));
typedef float f32x4 __attribute__((ext_vector_type(4)));
typedef unsigned short ushort8v __attribute__((ext_vector_type(8)));
#define MFMA(a, b, c) __builtin_amdgcn_mfma_f32_16x16x32_bf16(a, b, c, 0, 0, 0)

__device__ __forceinline__ unsigned short to_bf16(float x) {
    return (unsigned short)((__float_as_uint(x) + 0x8000u) >> 16);
}

__device__ __forceinline__ ushort8v pack8(float4 a, float4 b) {
    ushort8v u;
    u[0] = to_bf16(a.x); u[1] = to_bf16(a.y); u[2] = to_bf16(a.z); u[3] = to_bf16(a.w);
    u[4] = to_bf16(b.x); u[5] = to_bf16(b.y); u[6] = to_bf16(b.z); u[7] = to_bf16(b.w);
    return u;
}

// ---------------- prepass: V side only, XCD-aligned ----------------
__global__ __launch_bounds__(256) void prepass_kernel(
    const float* __restrict__ kv, unsigned short* __restrict__ frag,
    float* __restrict__ out)
{
    if (blockIdx.x == 0 && threadIdx.x < 8)
        out[8 * NTOK * 3 + threadIdx.x] = LPCONST;   // seed log-prob slots

    const int b = blockIdx.x & 7;                    // XCD-local to actor's b
    const int g = (blockIdx.x >> 3) * 256 + threadIdx.x;   // 0..16383 per b
    const int lane = g & 63;
    const int kc   = (g >> 6) & 3;
    const int tile = (g >> 8) & 63;

    const int row = tile * 16 + (lane & 15);
    const int kof = kc * 32 + (lane >> 4) * 8;
    const float* gp = kv + ((size_t)b * NTOK + row) * 512 + 128 + kof;  // v_mu
    const float4 m0 = *(const float4*)gp;
    const float4 m1 = *(const float4*)(gp + 4);
    const float4 s0 = *(const float4*)(gp + 256);   // v_sigma (col 384+kof)
    const float4 s1 = *(const float4*)(gp + 260);

    unsigned short* cp = frag + (size_t)(b * 64 + tile) * 4096 + kc * 1024 + lane * 8;
    *(ushort8v*)(cp + 0)   = pack8(m0, m1);   // arr0 mu
    *(ushort8v*)(cp + 512) = pack8(s0, s1);   // arr1 sg
}

// ---------------- gemm^T + geometry, 32 i x 256 j per block ----------------
__global__ __launch_bounds__(512) void actor_kernel(
    const float* __restrict__ kv, const unsigned short* __restrict__ fragV,
    const float* __restrict__ pos, float* __restrict__ partial)
{
    const int t = threadIdx.x;
    const int w = t >> 6;        // wave 0..7
    const int lane = t & 63;
    const int q = lane >> 4;
    const int r16 = lane & 15;
    const int b   = blockIdx.x & 7;
    const int jh  = (blockIdx.x >> 3) & 3;   // j quarter
    const int ibx = blockIdx.x >> 5;         // 0..31
    const int i0 = ibx * 32;

    const float* kvb  = kv + (size_t)b * NTOK * 512;
    const float* posb = pos + (size_t)b * NTOK * 3;

    __shared__ __align__(16) unsigned short sK[8192];   // 16 KB: 2 K tiles; wacc aliases
    __shared__ __align__(16) float spi[32 * 3];         // this block's i-positions
    __shared__ __align__(16) float spj[256 * 3];        // this block's j-quarter positions
    float* wacc = (float*)sK;                           // 8*32*6 = 1536 floats = 6 KB

    // ---- stage K: fp32 rows -> bf16 MFMA-fragment order in LDS ----
    // thread t -> row ri = t>>4 (0..31), col-group cg = t&15 (8 cols).
    // k-cols cg*8..+7: kc = cg>>2, g = cg&3; frag ushort idx =
    // tile*4096 + kc*1024 + arr*512 + (g*16 + row%16)*8 + e.
    {
        const int ri = t >> 4;
        const int cg = t & 15;
        const float* gp = kvb + (size_t)(i0 + ri) * 512 + cg * 8;
        const float4 m0 = *(const float4*)(gp);
        const float4 m1 = *(const float4*)(gp + 4);
        const float4 s0 = *(const float4*)(gp + 256);
        const float4 s1 = *(const float4*)(gp + 260);
        unsigned short* dp = sK + (ri >> 4) * 4096 + (cg >> 2) * 1024
                           + ((cg & 3) * 16 + (ri & 15)) * 8;
        *(ushort8v*)(dp)       = pack8(m0, m1);   // arr0 mu
        *(ushort8v*)(dp + 512) = pack8(s0, s1);   // arr1 sg
    }
    // ---- stage only the positions this block touches ----
    if (t < 216) {
        if (t < 24)  *(float4*)&spi[t * 4] = *(const float4*)&posb[i0 * 3 + t * 4];
        else { const int v = t - 24;
               *(float4*)&spj[v * 4] = *(const float4*)&posb[jh * 768 + v * 4]; }
    }
    __syncthreads();

    // lane's i per tile (C column) is fixed
    float pix[2], piy[2], piz[2];
    #pragma unroll
    for (int tile = 0; tile < 2; ++tile) {
        pix[tile] = spi[(tile * 16 + r16) * 3 + 0];
        piy[tile] = spi[(tile * 16 + r16) * 3 + 1];
        piz[tile] = spi[(tile * 16 + r16) * 3 + 2];
    }

    float am[2][3] = {};   // [tile][c]
    float al[2][3] = {};

    const int jtile0 = jh * 16 + w * 2;   // this wave's first 16-j tile
    const unsigned short* vbase =
        fragV + (size_t)(b * 64 + jtile0) * 4096 + lane * 8;
    const int klofs = lane * 8;

    #pragma unroll
    for (int jt = 0; jt < 2; ++jt) {
        const unsigned short* vp = vbase + jt * 4096;
        f32x4 accm[2], accs[2];
        #pragma unroll
        for (int tile = 0; tile < 2; ++tile) {
            accm[tile] = (f32x4){0.f, 0.f, 0.f, 0.f};
            accs[tile] = (f32x4){0.f, 0.f, 0.f, 0.f};
        }
        #pragma unroll
        for (int kc = 0; kc < 4; ++kc) {
            const bf16x8 Vm = *(const bf16x8*)(vp + kc * 1024);
            const bf16x8 Vs = *(const bf16x8*)(vp + kc * 1024 + 512);
            #pragma unroll
            for (int tile = 0; tile < 2; ++tile) {
                const bf16x8 Km = *(const bf16x8*)&sK[tile * 4096 + kc * 1024 + klofs];
                const bf16x8 Ks = *(const bf16x8*)&sK[tile * 4096 + kc * 1024 + 512 + klofs];
                accm[tile] = MFMA(Vm, Km, accm[tile]);   // C[row=j][col=i]
                accs[tile] = MFMA(Vs, Ks, accs[tile]);
            }
        }
        // ---- fold this tile's 4 j's (rows q*4+reg) into per-i sums ----
        const int jl = (w * 2 + jt) * 16 + q * 4;   // local j in [0,256)
        #pragma unroll
        for (int reg = 0; reg < 4; ++reg) {
            const float* pj = &spj[(jl + reg) * 3];  // LDS broadcast
            const float pjx = pj[0], pjy = pj[1], pjz = pj[2];
            #pragma unroll
            for (int tile = 0; tile < 2; ++tile) {
                const float dx = pix[tile] - pjx;
                const float dy = piy[tile] - pjy;
                const float dz = piz[tile] - pjz;
                const float d2 = dx * dx + dy * dy + dz * dz;
                const float inv = d2 > 0.f ? rsqrtf(d2) : 0.f;  // i==j -> 0
                const float wm = accm[tile][reg] * inv;
                const float ws = accs[tile][reg] * inv;
                am[tile][0] = fmaf(dx, wm, am[tile][0]);
                am[tile][1] = fmaf(dy, wm, am[tile][1]);
                am[tile][2] = fmaf(dz, wm, am[tile][2]);
                al[tile][0] = fmaf(dx, ws, al[tile][0]);
                al[tile][1] = fmaf(dy, ws, al[tile][1]);
                al[tile][2] = fmaf(dz, ws, al[tile][2]);
            }
        }
    }

    // ---- reduce over the 4 q-groups (lanes r16, +16, +32, +48) ----
    #pragma unroll
    for (int tile = 0; tile < 2; ++tile)
        #pragma unroll
        for (int c = 0; c < 3; ++c) {
            float vm = am[tile][c], vl = al[tile][c];
            vm += __shfl_xor(vm, 16, 64); vm += __shfl_xor(vm, 32, 64);
            vl += __shfl_xor(vl, 16, 64); vl += __shfl_xor(vl, 32, 64);
            am[tile][c] = vm; al[tile][c] = vl;
        }

    // ---- cross-wave combine via LDS (wacc aliases sK: sync first) ----
    __syncthreads();   // all waves done reading sK before overwrite
    if (lane < 16) {
        #pragma unroll
        for (int tile = 0; tile < 2; ++tile) {
            float* p = wacc + (w * 32 + tile * 16 + r16) * 6;
            p[0] = am[tile][0]; p[1] = am[tile][1]; p[2] = am[tile][2];
            p[3] = al[tile][0]; p[4] = al[tile][1]; p[5] = al[tile][2];
        }
    }
    __syncthreads();
    if (t < 192) {
        float v = 0.f;
        #pragma unroll
        for (int ww = 0; ww < 8; ++ww) v += wacc[ww * 192 + t];
        const int row = t / 6, c = t - row * 6;
        partial[((size_t)((jh * 8 + b) * NTOK) + i0 + row) * 6 + c] = v;
    }
}

// ---------------- tail ----------------
__global__ __launch_bounds__(64) void actor_tail_kernel(
    const float* __restrict__ partial, const float* __restrict__ eps,
    float* __restrict__ out)
{
    const int b = blockIdx.x >> 4;
    const int i = (blockIdx.x & 15) * 64 + threadIdx.x;
    const int gi = b * NTOK + i;

    float am[3] = {}, al[3] = {};
    #pragma unroll
    for (int jh = 0; jh < 4; ++jh) {
        const float* p = partial + (((size_t)jh * 8 + b) * NTOK + i) * 6;
        const float2 v0 = *(const float2*)(p);
        const float2 v1 = *(const float2*)(p + 2);
        const float2 v2 = *(const float2*)(p + 4);
        am[0] += v0.x; am[1] += v0.y; am[2] += v1.x;
        al[0] += v1.y; al[1] += v2.x; al[2] += v2.y;
    }

    float lp = 0.f;
    #pragma unroll
    for (int c = 0; c < 3; ++c) {
        const float als = fminf(fmaxf(al[c], -20.f), 2.f);
        const float sd = __expf(als);
        const float e = eps[gi * 3 + c];
        const float pre = fmaf(sd, e, am[c]);
        // E = exp(-2|pre|):  tanh(pre) = sign*(1-E)/(1+E);
        // softplus(2pre)+softplus(-2pre) = 2|pre| + 2*log(1+E)
        const float a2 = 2.f * fabsf(pre);
        const float E = __expf(-a2);
        const float th = (1.f - E) / (1.f + E);
        out[gi * 3 + c] = copysignf(th, pre) * 0.01f;
        lp += fmaf(-0.5f * e, e, -als) - 2.3052328944f + a2 + 2.f * __logf(1.f + E);
    }

    #pragma unroll
    for (int m = 1; m < 64; m <<= 1) lp += __shfl_xor(lp, m, 64);
    if (threadIdx.x == 0) atomicAdd(out + NTOK * 8 * 3 + b, lp);
}

extern "C" void kernel_launch(void* const* d_in, const int* in_sizes, int n_in,
                              void* d_out, int out_size, void* d_ws, size_t ws_size,
                              hipStream_t stream) {
    const float* kv = (const float*)d_in[0];
    const float* pos = (const float*)d_in[1];
    const float* eps = (const float*)d_in[2];
    float* out = (float*)d_out;
    unsigned short* fragV = (unsigned short*)d_ws;                // 4 MiB
    float* partial = (float*)((char*)d_ws + 4194304);             // 768 KiB

    prepass_kernel<<<dim3(512), 256, 0, stream>>>(kv, fragV, out);
    actor_kernel<<<dim3(1024), 512, 0, stream>>>(kv, fragV, pos, partial);
    actor_tail_kernel<<<dim3(128), 64, 0, stream>>>(partial, eps, out);
}